// Round 15
// baseline (213.044 us; speedup 1.0000x reference)
//
#include <hip/hip_runtime.h>
#include <math.h>

// Problem constants (C = RC = 1)
#define BB 2
#define SS 1024
#define DD 1024
#define NH 16
#define DH 64
#define MAXN 0.996f   // (1 - PROJ_EPS)/RC

typedef __attribute__((ext_vector_type(8))) short bf16x8;  // MFMA A/B frag (4 VGPRs)
typedef __attribute__((ext_vector_type(4))) float f32x4;   // MFMA C/D frag

__device__ __forceinline__ float xor_sum16(float v){
  v += __shfl_xor(v, 1, 64);
  v += __shfl_xor(v, 2, 64);
  v += __shfl_xor(v, 4, 64);
  v += __shfl_xor(v, 8, 64);
  return v;
}

__device__ __forceinline__ unsigned short f2bf(float x){
  unsigned u = __builtin_bit_cast(unsigned, x);
  unsigned r = u + 0x7FFFu + ((u >> 16) & 1u);   // RNE
  return (unsigned short)(r >> 16);
}
__device__ __forceinline__ float bf2f(unsigned short b){
  unsigned u = ((unsigned)b) << 16;
  return __builtin_bit_cast(float, u);
}

// async global->LDS DMA: per-lane 16B from g, landing at wave-uniform s + lane*16
__device__ __forceinline__ void async_copy16(const unsigned short* g, unsigned short* s){
  __builtin_amdgcn_global_load_lds(
      (const __attribute__((address_space(1))) unsigned int*)g,
      (__attribute__((address_space(3))) unsigned int*)s,
      16, 0, 0);
}

// ---------------- K1: fused prep (one launch) ----------------
// blocks [0,48): col_stats -> acol=2cosh(2r)/zn, bcol=sinh(2r), scol=2zn
// blocks [48,1072): convert_x (split-bf16) + fused per-row ||x||^2 (2 rows/block)
// blocks [1072,1840): convert_zt (z -> split-bf16 transposed ZT[mat][n][k])
__global__ __launch_bounds__(256) void prep_kernel(
    const float* __restrict__ hs,
    const float* __restrict__ zq, const float* __restrict__ zk, const float* __restrict__ zv,
    const float* __restrict__ rq, const float* __restrict__ rk, const float* __restrict__ rv,
    float* __restrict__ acol, float* __restrict__ bcol, float* __restrict__ scol,
    float* __restrict__ cx2,
    unsigned short* __restrict__ Xhi, unsigned short* __restrict__ Xlo,
    unsigned short* __restrict__ ZThi, unsigned short* __restrict__ ZTlo)
{
  __shared__ unsigned shbuf[64 * 69];     // 17.6 KB, aliased per role
  const int bid = blockIdx.x;
  const int tid = threadIdx.x;

  if (bid < 48) {
    // ---- col_stats ----
    const int m = bid >> 4, xb = bid & 15;
    const float* z = (m == 0) ? zq : ((m == 1) ? zk : zv);
    const float* r = (m == 0) ? rq : ((m == 1) ? rk : rv);
    const int col = xb * 64 + (tid & 63);
    const int slice = tid >> 6;
    float acc = 0.0f;
    for (int i = slice * 256; i < slice * 256 + 256; ++i) {
      float t = z[(size_t)i * DD + col]; acc = fmaf(t, t, acc);
    }
    float (*red)[64] = (float(*)[64])shbuf;
    red[slice][tid & 63] = acc;
    __syncthreads();
    if (slice == 0) {
      const int c = tid & 63;
      float a = red[0][c] + red[1][c] + red[2][c] + red[3][c];
      float n = fmaxf(sqrtf(a), 1e-15f);
      float rr = 2.0f * r[col];
      acol[m * DD + col] = 2.0f * coshf(rr) / n;
      bcol[m * DD + col] = sinhf(rr);
      scol[m * DD + col] = 2.0f * n;
    }
  } else if (bid < 48 + 1024) {
    // ---- convert_x + row ||x||^2 (rows 2b, 2b+1) ----
    const int b = bid - 48;
    const size_t g0 = (size_t)b * 2048 + (size_t)tid * 8;
    float acc = 0.0f;
    #pragma unroll
    for (int h = 0; h < 2; ++h) {
      float4 v = *(const float4*)(hs + g0 + 4 * h);
      float a[4] = {v.x, v.y, v.z, v.w};
      ushort4 hv, lv;
      unsigned short* hp = (unsigned short*)&hv;
      unsigned short* lp = (unsigned short*)&lv;
      #pragma unroll
      for (int j = 0; j < 4; ++j) {
        acc = fmaf(a[j], a[j], acc);
        unsigned short hi = f2bf(a[j]);
        hp[j] = hi;
        lp[j] = f2bf(a[j] - bf2f(hi));
      }
      *(ushort4*)(Xhi + g0 + 4 * h) = hv;
      *(ushort4*)(Xlo + g0 + 4 * h) = lv;
    }
    #pragma unroll
    for (int m = 1; m < 64; m <<= 1) acc += __shfl_xor(acc, m, 64);
    float* red = (float*)shbuf;
    const int wave = tid >> 6, lane = tid & 63;
    if (lane == 0) red[wave] = acc;
    __syncthreads();
    if (tid == 0)   cx2[2 * b]     = red[0] + red[1];
    if (tid == 128) cx2[2 * b + 1] = red[2] + red[3];
  } else {
    // ---- convert_zt ----
    const int b2 = bid - 1072;
    const int kt = b2 & 15, nt = (b2 >> 4) & 15, mat = b2 >> 8;
    const float* z = (mat == 0) ? zq : ((mat == 1) ? zk : zv);
    unsigned (*T)[69] = (unsigned(*)[69])shbuf;
    #pragma unroll
    for (int i = 0; i < 4; ++i) {
      const int g = tid + 256 * i;
      const int kr = g >> 4, nc = (g & 15) * 4;
      float4 v = *(const float4*)(z + (size_t)(kt * 64 + kr) * DD + nt * 64 + nc);
      float a[4] = {v.x, v.y, v.z, v.w};
      #pragma unroll
      for (int j = 0; j < 4; ++j) {
        unsigned short hi = f2bf(a[j]);
        unsigned short lo = f2bf(a[j] - bf2f(hi));
        T[kr][nc + j] = ((unsigned)lo << 16) | (unsigned)hi;
      }
    }
    __syncthreads();
    #pragma unroll
    for (int i = 0; i < 4; ++i) {
      const int g = tid + 256 * i;
      const int nr = g >> 4, kc = (g & 15) * 4;
      ushort4 hv, lv;
      unsigned short* hp = (unsigned short*)&hv;
      unsigned short* lp = (unsigned short*)&lv;
      #pragma unroll
      for (int j = 0; j < 4; ++j) {
        unsigned u = T[kc + j][nr];
        hp[j] = (unsigned short)(u & 0xFFFFu);
        lp[j] = (unsigned short)(u >> 16);
      }
      const size_t ob = ((size_t)mat * DD + nt * 64 + nr) * DD + kt * 64 + kc;
      *(ushort4*)(ZThi + ob) = hv;
      *(ushort4*)(ZTlo + ob) = lv;
    }
  }
}

// ---------------- K2: split-bf16 MFMA GEMM (x@z) + Poincare-linear epilogue ----------------
// v10 = v9 + PHASE-STAGGERED K-loop. Round-14 lesson: conflicts fixed (4.85M->131K)
// but time flat -> the stall is LOCKSTEP: 3 identical blocks/CU hit their
// vmcnt(0)+barrier drains simultaneously, so no block's compute covers another's
// DMA latency. GEMM accumulation is K-order independent -> each block starts its
// K-loop at phase (block-dependent, {0,8,16,24}) and wraps; co-resident blocks'
// memory and compute phases now interleave.
__global__ __launch_bounds__(256, 3) void gemm_mfma_kernel(
    const unsigned short* __restrict__ Xhi, const unsigned short* __restrict__ Xlo,
    const unsigned short* __restrict__ ZThi, const unsigned short* __restrict__ ZTlo,
    const float* __restrict__ acol, const float* __restrict__ bcol, const float* __restrict__ scol,
    const float* __restrict__ cx2,
    unsigned short* __restrict__ Qhi, unsigned short* __restrict__ Qlo,
    unsigned short* __restrict__ Khi, unsigned short* __restrict__ Klo,
    unsigned short* __restrict__ GThi, unsigned short* __restrict__ GTlo,
    float* __restrict__ q2, float* __restrict__ k2, float* __restrict__ gm1)
{
  // per buffer (halfwords): Xh [0,2048) Xl [2048,4096) Zh [4096,8192) Zl [8192,12288)
  __shared__ unsigned short S[2][12288];     // 48 KB -> 3 blocks/CU

  const int mat = blockIdx.z;
  float* Stat = (mat == 0) ? q2 : ((mat == 1) ? k2 : gm1);
  unsigned short* Bh = (mat == 0) ? Qhi : Khi;
  unsigned short* Bl = (mat == 0) ? Qlo : Klo;

  const int n0 = blockIdx.x * 128;
  const int m0 = blockIdx.y * 64;
  const int tid = threadIdx.x;
  const int wave = tid >> 6, lane = tid & 63;
  const int tx = lane & 15, quad = lane >> 4;
  const int wrow = wave & 1;                 // rows [32*wrow, +32)
  const int wcol = wave >> 1;                // cols [64*wcol, +64) = head wcol

  // desync phase: mix all block coords so same-CU blocks differ
  const int phase = ((blockIdx.x + blockIdx.y + 11 * blockIdx.z) & 3) * 8;

  // DMA slice mapping with chunk swizzle (round-14): row r = lane>>2, global chunk
  // c = ((lane&3) - (r>>1)) & 3 stored at physical chunk lane&3.
  const int l4r = lane >> 2;
  const int l4c = 8 * (((lane & 3) - (l4r >> 1)) & 3);
  auto slice_ptr = [&](int si) -> const unsigned short* {
    if (si < 8) {
      const unsigned short* base = (si < 4) ? Xhi : Xlo;
      const int r16 = (si & 3) * 16;
      return base + (size_t)(m0 + r16 + l4r) * DD + l4c;
    } else {
      const unsigned short* base = (si < 16) ? ZThi : ZTlo;
      const int r16 = ((si - 8) & 7) * 16;
      return base + ((size_t)mat * DD + n0 + r16 + l4r) * DD + l4c;
    }
  };
  const int s0 = 6 * wave;
  const unsigned short* p0 = slice_ptr(s0 + 0);
  const unsigned short* p1 = slice_ptr(s0 + 1);
  const unsigned short* p2 = slice_ptr(s0 + 2);
  const unsigned short* p3 = slice_ptr(s0 + 3);
  const unsigned short* p4 = slice_ptr(s0 + 4);
  const unsigned short* p5 = slice_ptr(s0 + 5);
  const int o0 = 512 * (s0 + 0), o1 = 512 * (s0 + 1), o2 = 512 * (s0 + 2);
  const int o3 = 512 * (s0 + 3), o4 = 512 * (s0 + 4), o5 = 512 * (s0 + 5);

  // frag-read chunk offset: physical chunk of global chunk `quad` for row tx
  const int koff = 8 * ((quad + (tx >> 1)) & 3);

  const f32x4 z4 = {0.f, 0.f, 0.f, 0.f};
  f32x4 d00 = z4, d01 = z4, d02 = z4, d03 = z4;   // mb=0
  f32x4 d10 = z4, d11 = z4, d12 = z4, d13 = z4;   // mb=1

  // prologue: tile (phase) -> buffer 0
  {
    const int ko = phase * 32;
    async_copy16(p0 + ko, &S[0][o0]); async_copy16(p1 + ko, &S[0][o1]);
    async_copy16(p2 + ko, &S[0][o2]); async_copy16(p3 + ko, &S[0][o3]);
    async_copy16(p4 + ko, &S[0][o4]); async_copy16(p5 + ko, &S[0][o5]);
  }

  for (int kt = 0; kt < 32; ++kt) {
    __syncthreads();                         // drains current tile's DMA
    if (kt < 31) {                           // issue tile (kt+1+phase)&31 -> other buffer
      const int ko = (((kt + 1 + phase) & 31) * 32);
      unsigned short* Bn = S[(kt + 1) & 1];
      async_copy16(p0 + ko, Bn + o0); async_copy16(p1 + ko, Bn + o1);
      async_copy16(p2 + ko, Bn + o2); async_copy16(p3 + ko, Bn + o3);
      async_copy16(p4 + ko, Bn + o4); async_copy16(p5 + ko, Bn + o5);
    }
    const unsigned short* Bc = S[kt & 1];
    const int ar = 32 * wrow + tx;
    bf16x8 a_h0 = *(const bf16x8*)&Bc[ar * 32 + koff];
    bf16x8 a_l0 = *(const bf16x8*)&Bc[2048 + ar * 32 + koff];
    bf16x8 a_h1 = *(const bf16x8*)&Bc[(ar + 16) * 32 + koff];
    bf16x8 a_l1 = *(const bf16x8*)&Bc[2048 + (ar + 16) * 32 + koff];

#define DO_NB(NB, C0, C1) { \
      const int brow = 16 * (4 * wcol + NB) + tx; \
      bf16x8 b_h = *(const bf16x8*)&Bc[4096 + brow * 32 + koff]; \
      bf16x8 b_l = *(const bf16x8*)&Bc[8192 + brow * 32 + koff]; \
      C0 = __builtin_amdgcn_mfma_f32_16x16x32_bf16(a_h0, b_h, C0, 0, 0, 0); \
      C0 = __builtin_amdgcn_mfma_f32_16x16x32_bf16(a_h0, b_l, C0, 0, 0, 0); \
      C0 = __builtin_amdgcn_mfma_f32_16x16x32_bf16(a_l0, b_h, C0, 0, 0, 0); \
      C1 = __builtin_amdgcn_mfma_f32_16x16x32_bf16(a_h1, b_h, C1, 0, 0, 0); \
      C1 = __builtin_amdgcn_mfma_f32_16x16x32_bf16(a_h1, b_l, C1, 0, 0, 0); \
      C1 = __builtin_amdgcn_mfma_f32_16x16x32_bf16(a_l1, b_h, C1, 0, 0, 0); }
    DO_NB(0, d00, d10)
    DO_NB(1, d01, d11)
    DO_NB(2, d02, d12)
    DO_NB(3, d03, d13)
#undef DO_NB
  }

  const int head = blockIdx.x * 2 + wcol;
  unsigned* Tr = (unsigned*)&S[0][0];        // reuse staging LDS (mat==2 only)
  if (mat == 2) __syncthreads();             // all waves done with S before reuse

  #pragma unroll
  for (int mb = 0; mb < 2; ++mb) {
    const f32x4 e0 = mb ? d10 : d00;
    const f32x4 e1 = mb ? d11 : d01;
    const f32x4 e2 = mb ? d12 : d02;
    const f32x4 e3 = mb ? d13 : d03;
    #pragma unroll
    for (int r = 0; r < 4; ++r) {
      const int sl = 32 * wrow + 16 * mb + 4 * quad + r;
      const int row = m0 + sl;
      const float c2 = cx2[row];
      const float inv = 1.0f / fmaxf(1.0f - c2, 1e-15f);
      const float onec = 1.0f + c2;
      float yv[4];
      #pragma unroll
      for (int nb = 0; nb < 4; ++nb) {
        const float accv = (nb == 0) ? e0[r] : (nb == 1) ? e1[r] : (nb == 2) ? e2[r] : e3[r];
        const int col = mat * DD + n0 + 64 * wcol + 16 * nb + tx;
        const float u = fmaf(accv, acol[col], -(onec * bcol[col])) * inv;
        const float a = fabsf(u);
        const float t = a + sqrtf(fmaf(a, a, 1.0f));
        const float p = __builtin_amdgcn_exp2f(scol[col] * __builtin_amdgcn_logf(t));
        float y = 0.5f * (p - __builtin_amdgcn_rcpf(p));
        yv[nb] = copysignf(y, u);
      }
      const int b = row >> 10, s = row & 1023;
      float n2 = 0.f;
      #pragma unroll
      for (int j = 0; j < 4; ++j) n2 = fmaf(yv[j], yv[j], n2);
      n2 = xor_sum16(n2);
      float n = fmaxf(sqrtf(n2), 1e-15f);
      float s1 = (n > MAXN) ? (MAXN / n) : 1.0f;      // project #1
      n2 = n2 * s1 * s1;
      float f = 1.0f / (1.0f + sqrtf(1.0f + n2));     // exp-map scaling
      float fs = s1 * f;
      n2 = n2 * f * f;
      float nb2 = fmaxf(sqrtf(n2), 1e-15f);
      float s2f = (nb2 > MAXN) ? (MAXN / nb2) : 1.0f; // project #2
      fs *= s2f;
      n2 = n2 * s2f * s2f;

      const size_t bh = (size_t)(b * NH + head);
      const size_t outbase = (bh * SS + s) * DH;
      if (mat == 2) {
        const float gamma = 2.0f / fmaxf(1.0f - n2, 1e-15f);
        #pragma unroll
        for (int j = 0; j < 4; ++j) {
          const float v = yv[j] * fs * gamma;
          const unsigned short hi = f2bf(v);
          const unsigned short lo = f2bf(v - bf2f(hi));
          Tr[(wcol * 64 + sl) * 65 + 16 * j + tx] = ((unsigned)lo << 16) | (unsigned)hi;
        }
        if (tx == 0) Stat[bh * SS + s] = gamma - 1.0f;
      } else {
        #pragma unroll
        for (int j = 0; j < 4; ++j) {
          const float v = yv[j] * fs;
          const unsigned short hi = f2bf(v);
          const unsigned short lo = f2bf(v - bf2f(hi));
          Bh[outbase + 16 * j + tx] = hi;
          Bl[outbase + 16 * j + tx] = lo;
        }
        if (tx == 0) Stat[bh * SS + s] = n2;
      }
    }
  }

  if (mat == 2) {                            // cooperative transposed writeout
    __syncthreads();
    const int bb = m0 >> 10, sbase = m0 & 1023;
    #pragma unroll
    for (int i = 0; i < 2; ++i) {
      const int task = tid + 256 * i;        // 512 tasks: 128 (h,dh) rows x 4 s-chunks
      const int rowid = task >> 2;
      const int hh = rowid >> 6, dh = rowid & 63;
      const int sc = (task & 3) * 16;
      unsigned short hbuf[16] __attribute__((aligned(16)));
      unsigned short lbuf[16] __attribute__((aligned(16)));
      #pragma unroll
      for (int s = 0; s < 16; ++s) {
        unsigned u = Tr[(hh * 64 + sc + s) * 65 + dh];
        hbuf[s] = (unsigned short)(u & 0xFFFFu);
        lbuf[s] = (unsigned short)(u >> 16);
      }
      const int hg = blockIdx.x * 2 + hh;
      const size_t ob = (((size_t)(bb * NH + hg)) * DH + dh) * SS + sbase + sc;
      *(uint4*)(GThi + ob)     = *(uint4*)&hbuf[0];
      *(uint4*)(GThi + ob + 8) = *(uint4*)&hbuf[8];
      *(uint4*)(GTlo + ob)     = *(uint4*)&lbuf[0];
      *(uint4*)(GTlo + ob + 8) = *(uint4*)&lbuf[8];
    }
  }
}

// ---------------- K3: MFMA flash-style hyperbolic attention ----------
// v6 = v5 (LDK=88 bank spread) + PHASE-STAGGERED key-tile loop. The softmax-free
// formulation makes (dden, oacc) accumulation key-order independent, so each
// block starts at a block-dependent tile and wraps -> co-resident blocks desync.
__global__ __launch_bounds__(256) void flash_attn_kernel(
    const unsigned short* __restrict__ Qhi, const unsigned short* __restrict__ Qlo,
    const unsigned short* __restrict__ Khi, const unsigned short* __restrict__ Klo,
    const unsigned short* __restrict__ GThi, const unsigned short* __restrict__ GTlo,
    const float* __restrict__ q2a, const float* __restrict__ k2a, const float* __restrict__ gm1a,
    const float* __restrict__ mask, float* __restrict__ out)
{
  constexpr int LDK = 88;
  __shared__ unsigned short Ks_hi[64 * LDK];
  __shared__ unsigned short Ks_lo[64 * LDK];
  __shared__ unsigned short Gs_hi[64 * LDK];
  __shared__ unsigned short Gs_lo[64 * LDK];
  __shared__ unsigned short Ps_hi[64 * LDK];
  __shared__ unsigned short Ps_lo[64 * LDK];
  __shared__ float k2s[64], ik2s[64], gm1s[64], ems[64];

  const int qt = blockIdx.x, h = blockIdx.y, b = blockIdx.z;
  const int bh = b * NH + h;
  const int tid = threadIdx.x;
  const int wave = tid >> 6, lane = tid & 63;
  const int tx = lane & 15, quad = lane >> 4;
  const int r0 = qt * 64;
  const int phase = (qt + h + 5 * b) & 15;   // desync co-resident blocks

  bf16x8 qa_h[2], qa_l[2];
  {
    const size_t qoff = ((size_t)bh * SS + r0 + 16 * wave + tx) * DH;
    #pragma unroll
    for (int kc = 0; kc < 2; ++kc) {
      qa_h[kc] = *(const bf16x8*)(Qhi + qoff + 32 * kc + 8 * quad);
      qa_l[kc] = *(const bf16x8*)(Qlo + qoff + 32 * kc + 8 * quad);
    }
  }
  float q2r[4], iq2[4];
  #pragma unroll
  for (int r = 0; r < 4; ++r) {
    q2r[r] = q2a[(size_t)bh * SS + r0 + 16 * wave + 4 * quad + r];
    iq2[r] = 2.0f / fmaxf(1.0f - q2r[r], 1e-15f);
  }

  const f32x4 zero4 = {0.f, 0.f, 0.f, 0.f};
  f32x4 oacc[4] = {zero4, zero4, zero4, zero4};
  float dden[4] = {0.f, 0.f, 0.f, 0.f};

  const int c0 = tid, c1 = tid + 256;
  const int sr0 = c0 >> 3, sc0 = (c0 & 7) * 8;
  const int sr1 = c1 >> 3, sc1 = (c1 & 7) * 8;

  const size_t kbase = (size_t)bh * SS * DH;
  const size_t gbase = (size_t)bh * DH * SS;

  // prologue prefetch: tile (phase)
  uint4 pk_h0, pk_h1, pk_l0, pk_l1, pg_h0, pg_h1, pg_l0, pg_l1;
  float p_k2 = 0.f, p_gm1 = 0.f, p_ms = 0.f;
  {
    const int t0 = phase * 64;
    const size_t kb_ = kbase + (size_t)t0 * DH;
    const size_t gb_ = gbase + t0;
    pk_h0 = *(const uint4*)(Khi + kb_ + (size_t)sr0 * DH + sc0);
    pk_h1 = *(const uint4*)(Khi + kb_ + (size_t)sr1 * DH + sc1);
    pk_l0 = *(const uint4*)(Klo + kb_ + (size_t)sr0 * DH + sc0);
    pk_l1 = *(const uint4*)(Klo + kb_ + (size_t)sr1 * DH + sc1);
    pg_h0 = *(const uint4*)(GThi + gb_ + (size_t)sr0 * SS + sc0);
    pg_h1 = *(const uint4*)(GThi + gb_ + (size_t)sr1 * SS + sc1);
    pg_l0 = *(const uint4*)(GTlo + gb_ + (size_t)sr0 * SS + sc0);
    pg_l1 = *(const uint4*)(GTlo + gb_ + (size_t)sr1 * SS + sc1);
    if (tid < 64) {
      p_k2  = k2a[(size_t)bh * SS + t0 + tid];
      p_gm1 = gm1a[(size_t)bh * SS + t0 + tid];
      p_ms  = mask[(size_t)b * SS + t0 + tid];
    }
  }

  for (int kt = 0; kt < 16; ++kt) {
    __syncthreads();                         // prev tile fully consumed
    *(uint4*)&Ks_hi[sr0 * LDK + sc0] = pk_h0;
    *(uint4*)&Ks_hi[sr1 * LDK + sc1] = pk_h1;
    *(uint4*)&Ks_lo[sr0 * LDK + sc0] = pk_l0;
    *(uint4*)&Ks_lo[sr1 * LDK + sc1] = pk_l1;
    *(uint4*)&Gs_hi[sr0 * LDK + sc0] = pg_h0;
    *(uint4*)&Gs_hi[sr1 * LDK + sc1] = pg_h1;
    *(uint4*)&Gs_lo[sr0 * LDK + sc0] = pg_l0;
    *(uint4*)&Gs_lo[sr1 * LDK + sc1] = pg_l1;
    if (tid < 64) {
      k2s[tid]  = p_k2;
      ik2s[tid] = 1.0f / fmaxf(1.0f - p_k2, 1e-15f);
      gm1s[tid] = p_gm1;
      ems[tid]  = __expf(p_ms);
    }
    __syncthreads();                         // tile ready
    if (kt < 15) {                           // prefetch tile (kt+1+phase)&15
      const int t1 = ((kt + 1 + phase) & 15) * 64;
      const size_t kb_ = kbase + (size_t)t1 * DH;
      const size_t gb_ = gbase + t1;
      pk_h0 = *(const uint4*)(Khi + kb_ + (size_t)sr0 * DH + sc0);
      pk_h1 = *(const uint4*)(Khi + kb_ + (size_t)sr1 * DH + sc1);
      pk_l0 = *(const uint4*)(Klo + kb_ + (size_t)sr0 * DH + sc0);
      pk_l1 = *(const uint4*)(Klo + kb_ + (size_t)sr1 * DH + sc1);
      pg_h0 = *(const uint4*)(GThi + gb_ + (size_t)sr0 * SS + sc0);
      pg_h1 = *(const uint4*)(GThi + gb_ + (size_t)sr1 * SS + sc1);
      pg_l0 = *(const uint4*)(GTlo + gb_ + (size_t)sr0 * SS + sc0);
      pg_l1 = *(const uint4*)(GTlo + gb_ + (size_t)sr1 * SS + sc1);
      if (tid < 64) {
        p_k2  = k2a[(size_t)bh * SS + t1 + tid];
        p_gm1 = gm1a[(size_t)bh * SS + t1 + tid];
        p_ms  = mask[(size_t)b * SS + t1 + tid];
      }
    }

    f32x4 sacc[4] = {zero4, zero4, zero4, zero4};
    #pragma unroll
    for (int kc = 0; kc < 2; ++kc) {
      const int ko = 32 * kc + 8 * quad;
      #pragma unroll
      for (int nb = 0; nb < 4; ++nb) {
        bf16x8 kh = *(const bf16x8*)&Ks_hi[(16 * nb + tx) * LDK + ko];
        bf16x8 kl = *(const bf16x8*)&Ks_lo[(16 * nb + tx) * LDK + ko];
        sacc[nb] = __builtin_amdgcn_mfma_f32_16x16x32_bf16(qa_h[kc], kh, sacc[nb], 0, 0, 0);
        sacc[nb] = __builtin_amdgcn_mfma_f32_16x16x32_bf16(qa_h[kc], kl, sacc[nb], 0, 0, 0);
        sacc[nb] = __builtin_amdgcn_mfma_f32_16x16x32_bf16(qa_l[kc], kh, sacc[nb], 0, 0, 0);
      }
    }

    float pb[4][4];
    #pragma unroll
    for (int nb = 0; nb < 4; ++nb) {
      const int key = 16 * nb + tx;
      const float k2v = k2s[key], ikv = ik2s[key], emv = ems[key], gmv = gm1s[key];
      #pragma unroll
      for (int r = 0; r < 4; ++r) {
        float sv = sacc[nb][r];
        float num = fmaxf(fmaf(-2.0f, sv, q2r[r] + k2v), 1e-15f);
        float e = num * iq2[r] * ikv;
        float g = fmaf(e, e, e + e);
        float z = 1.0f + e + __builtin_amdgcn_sqrtf(g);
        float w = emv * __builtin_amdgcn_rcpf(z);
        pb[r][nb] = w;
        dden[r] = fmaf(w, gmv, dden[r]);
      }
    }

    // write P into its own region; wave w owns rows [16w,16w+16) exclusively
    #pragma unroll
    for (int r = 0; r < 4; ++r) {
      const int prow = 16 * wave + 4 * quad + r;
      #pragma unroll
      for (int nb = 0; nb < 4; ++nb) {
        float w = pb[r][nb];
        unsigned short hi = f2bf(w);
        unsigned short lo = f2bf(w - bf2f(hi));
        Ps_hi[prow * LDK + 16 * nb + tx] = hi;
        Ps_lo[prow * LDK + 16 * nb + tx] = lo;
      }
    }
    // PV: same-wave LDS RAW only -> no barrier needed
    #pragma unroll
    for (int kc = 0; kc < 2; ++kc) {
      const int ko = 32 * kc + 8 * quad;
      bf16x8 ph = *(const bf16x8*)&Ps_hi[(16 * wave + tx) * LDK + ko];
      bf16x8 pl = *(const bf16x8*)&Ps_lo[(16 * wave + tx) * LDK + ko];
      #pragma unroll
      for (int nb = 0; nb < 4; ++nb) {
        bf16x8 gh = *(const bf16x8*)&Gs_hi[(16 * nb + tx) * LDK + ko];
        bf16x8 gl = *(const bf16x8*)&Gs_lo[(16 * nb + tx) * LDK + ko];
        oacc[nb] = __builtin_amdgcn_mfma_f32_16x16x32_bf16(ph, gh, oacc[nb], 0, 0, 0);
        oacc[nb] = __builtin_amdgcn_mfma_f32_16x16x32_bf16(ph, gl, oacc[nb], 0, 0, 0);
        oacc[nb] = __builtin_amdgcn_mfma_f32_16x16x32_bf16(pl, gh, oacc[nb], 0, 0, 0);
      }
    }
  }

  #pragma unroll
  for (int r = 0; r < 4; ++r) {
    float d = fmaxf(xor_sum16(dden[r]), 1e-10f);
    float invd = 1.0f / d;
    float tm[4]; float sq = 0.f;
    #pragma unroll
    for (int nb = 0; nb < 4; ++nb) { tm[nb] = oacc[nb][r] * invd; sq = fmaf(tm[nb], tm[nb], sq); }
    sq = xor_sum16(sq);
    const float f = 1.0f / (1.0f + sqrtf(fmaxf(1.0f - sq, 1e-15f)));
    const float n2 = sq * f * f;
    const float n = fmaxf(sqrtf(n2), 1e-15f);
    const float s2 = (n > MAXN) ? (MAXN / n) : 1.0f;
    const float fs = f * s2;
    const int qrow = r0 + 16 * wave + 4 * quad + r;
    #pragma unroll
    for (int nb = 0; nb < 4; ++nb)
      out[((size_t)(b * SS + qrow)) * DD + h * DH + 16 * nb + tx] = tm[nb] * fs;
  }
}

// ---------------- host ----------------
extern "C" void kernel_launch(void* const* d_in, const int* in_sizes, int n_in,
                              void* d_out, int out_size, void* d_ws, size_t ws_size,
                              hipStream_t stream) {
  const float* hs   = (const float*)d_in[0];
  const float* mask = (const float*)d_in[1];
  const float* qz   = (const float*)d_in[2];
  const float* qr   = (const float*)d_in[3];
  const float* kz   = (const float*)d_in[4];
  const float* kr   = (const float*)d_in[5];
  const float* vz   = (const float*)d_in[6];
  const float* vr   = (const float*)d_in[7];
  float* out = (float*)d_out;

  float* ws = (float*)d_ws;
  const size_t nQKV = (size_t)BB * NH * SS * DH;   // 2,097,152
  const size_t nStat = (size_t)BB * NH * SS;       // 32,768

  // fp32 region
  float* q2  = ws;
  float* k2  = q2 + nStat;
  float* gm1 = k2 + nStat;
  float* acol = gm1 + nStat;         // 3*1024 each
  float* bcol = acol + 3 * DD;
  float* scol = bcol + 3 * DD;
  float* cx2 = scol + 3 * DD;        // 2048

  // bf16 region (halfwords). gemm reads X/ZT while writing Q/K/GT -> all distinct.
  unsigned short* sb   = (unsigned short*)(cx2 + 2048);   // 16B-aligned
  unsigned short* Qhi  = sb;                  // 2M each
  unsigned short* Qlo  = Qhi + nQKV;
  unsigned short* Khi  = Qlo + nQKV;
  unsigned short* Klo  = Khi + nQKV;
  unsigned short* GThi = Klo + nQKV;
  unsigned short* GTlo = GThi + nQKV;
  unsigned short* Xhi  = GTlo + nQKV;
  unsigned short* Xlo  = Xhi + nQKV;
  unsigned short* ZThi = Xlo + nQKV;          // 3M each
  unsigned short* ZTlo = ZThi + 3 * (size_t)DD * DD;  // total 22M shorts = 44 MB

  prep_kernel<<<dim3(1840), 256, 0, stream>>>(
      hs, qz, kz, vz, qr, kr, vr, acol, bcol, scol, cx2, Xhi, Xlo, ZThi, ZTlo);
  gemm_mfma_kernel<<<dim3(8, 32, 3), 256, 0, stream>>>(
      Xhi, Xlo, ZThi, ZTlo, acol, bcol, scol, cx2,
      Qhi, Qlo, Khi, Klo, GThi, GTlo, q2, k2, gm1);
  flash_attn_kernel<<<dim3(16, NH, BB), 256, 0, stream>>>(
      Qhi, Qlo, Khi, Klo, GThi, GTlo, q2, k2, gm1, mask, out);
}

// Round 16
// 207.940 us; speedup vs baseline: 1.0245x; 1.0245x over previous
//
#include <hip/hip_runtime.h>
#include <math.h>

// Problem constants (C = RC = 1)
#define BB 2
#define SS 1024
#define DD 1024
#define NH 16
#define DH 64
#define MAXN 0.996f   // (1 - PROJ_EPS)/RC

typedef __attribute__((ext_vector_type(8))) short bf16x8;  // MFMA A/B frag (4 VGPRs)
typedef __attribute__((ext_vector_type(4))) float f32x4;   // MFMA C/D frag

__device__ __forceinline__ float xor_sum16(float v){
  v += __shfl_xor(v, 1, 64);
  v += __shfl_xor(v, 2, 64);
  v += __shfl_xor(v, 4, 64);
  v += __shfl_xor(v, 8, 64);
  return v;
}

__device__ __forceinline__ unsigned short f2bf(float x){
  unsigned u = __builtin_bit_cast(unsigned, x);
  unsigned r = u + 0x7FFFu + ((u >> 16) & 1u);   // RNE
  return (unsigned short)(r >> 16);
}
__device__ __forceinline__ float bf2f(unsigned short b){
  unsigned u = ((unsigned)b) << 16;
  return __builtin_bit_cast(float, u);
}

// async global->LDS DMA: per-lane 16B from g, landing at wave-uniform s + lane*16
__device__ __forceinline__ void async_copy16(const unsigned short* g, unsigned short* s){
  __builtin_amdgcn_global_load_lds(
      (const __attribute__((address_space(1))) unsigned int*)g,
      (__attribute__((address_space(3))) unsigned int*)s,
      16, 0, 0);
}

// ---------------- K1: fused prep (one launch) ----------------
// blocks [0,48): col_stats -> acol=2cosh(2r)/zn, bcol=sinh(2r), scol=2zn
// blocks [48,1072): convert_x (split-bf16) + fused per-row ||x||^2 (2 rows/block)
// blocks [1072,1840): convert_zt (z -> split-bf16 transposed ZT[mat][n][k])
__global__ __launch_bounds__(256) void prep_kernel(
    const float* __restrict__ hs,
    const float* __restrict__ zq, const float* __restrict__ zk, const float* __restrict__ zv,
    const float* __restrict__ rq, const float* __restrict__ rk, const float* __restrict__ rv,
    float* __restrict__ acol, float* __restrict__ bcol, float* __restrict__ scol,
    float* __restrict__ cx2,
    unsigned short* __restrict__ Xhi, unsigned short* __restrict__ Xlo,
    unsigned short* __restrict__ ZThi, unsigned short* __restrict__ ZTlo)
{
  __shared__ unsigned shbuf[64 * 69];     // 17.6 KB, aliased per role
  const int bid = blockIdx.x;
  const int tid = threadIdx.x;

  if (bid < 48) {
    // ---- col_stats ----
    const int m = bid >> 4, xb = bid & 15;
    const float* z = (m == 0) ? zq : ((m == 1) ? zk : zv);
    const float* r = (m == 0) ? rq : ((m == 1) ? rk : rv);
    const int col = xb * 64 + (tid & 63);
    const int slice = tid >> 6;
    float acc = 0.0f;
    for (int i = slice * 256; i < slice * 256 + 256; ++i) {
      float t = z[(size_t)i * DD + col]; acc = fmaf(t, t, acc);
    }
    float (*red)[64] = (float(*)[64])shbuf;
    red[slice][tid & 63] = acc;
    __syncthreads();
    if (slice == 0) {
      const int c = tid & 63;
      float a = red[0][c] + red[1][c] + red[2][c] + red[3][c];
      float n = fmaxf(sqrtf(a), 1e-15f);
      float rr = 2.0f * r[col];
      acol[m * DD + col] = 2.0f * coshf(rr) / n;
      bcol[m * DD + col] = sinhf(rr);
      scol[m * DD + col] = 2.0f * n;
    }
  } else if (bid < 48 + 1024) {
    // ---- convert_x + row ||x||^2 (rows 2b, 2b+1) ----
    const int b = bid - 48;
    const size_t g0 = (size_t)b * 2048 + (size_t)tid * 8;
    float acc = 0.0f;
    #pragma unroll
    for (int h = 0; h < 2; ++h) {
      float4 v = *(const float4*)(hs + g0 + 4 * h);
      float a[4] = {v.x, v.y, v.z, v.w};
      ushort4 hv, lv;
      unsigned short* hp = (unsigned short*)&hv;
      unsigned short* lp = (unsigned short*)&lv;
      #pragma unroll
      for (int j = 0; j < 4; ++j) {
        acc = fmaf(a[j], a[j], acc);
        unsigned short hi = f2bf(a[j]);
        hp[j] = hi;
        lp[j] = f2bf(a[j] - bf2f(hi));
      }
      *(ushort4*)(Xhi + g0 + 4 * h) = hv;
      *(ushort4*)(Xlo + g0 + 4 * h) = lv;
    }
    #pragma unroll
    for (int m = 1; m < 64; m <<= 1) acc += __shfl_xor(acc, m, 64);
    float* red = (float*)shbuf;
    const int wave = tid >> 6, lane = tid & 63;
    if (lane == 0) red[wave] = acc;
    __syncthreads();
    if (tid == 0)   cx2[2 * b]     = red[0] + red[1];
    if (tid == 128) cx2[2 * b + 1] = red[2] + red[3];
  } else {
    // ---- convert_zt ----
    const int b2 = bid - 1072;
    const int kt = b2 & 15, nt = (b2 >> 4) & 15, mat = b2 >> 8;
    const float* z = (mat == 0) ? zq : ((mat == 1) ? zk : zv);
    unsigned (*T)[69] = (unsigned(*)[69])shbuf;
    #pragma unroll
    for (int i = 0; i < 4; ++i) {
      const int g = tid + 256 * i;
      const int kr = g >> 4, nc = (g & 15) * 4;
      float4 v = *(const float4*)(z + (size_t)(kt * 64 + kr) * DD + nt * 64 + nc);
      float a[4] = {v.x, v.y, v.z, v.w};
      #pragma unroll
      for (int j = 0; j < 4; ++j) {
        unsigned short hi = f2bf(a[j]);
        unsigned short lo = f2bf(a[j] - bf2f(hi));
        T[kr][nc + j] = ((unsigned)lo << 16) | (unsigned)hi;
      }
    }
    __syncthreads();
    #pragma unroll
    for (int i = 0; i < 4; ++i) {
      const int g = tid + 256 * i;
      const int nr = g >> 4, kc = (g & 15) * 4;
      ushort4 hv, lv;
      unsigned short* hp = (unsigned short*)&hv;
      unsigned short* lp = (unsigned short*)&lv;
      #pragma unroll
      for (int j = 0; j < 4; ++j) {
        unsigned u = T[kc + j][nr];
        hp[j] = (unsigned short)(u & 0xFFFFu);
        lp[j] = (unsigned short)(u >> 16);
      }
      const size_t ob = ((size_t)mat * DD + nt * 64 + nr) * DD + kt * 64 + kc;
      *(ushort4*)(ZThi + ob) = hv;
      *(ushort4*)(ZTlo + ob) = lv;
    }
  }
}

// ---------------- K2: split-bf16 MFMA GEMM (x@z) + Poincare-linear epilogue ----------------
// v9 (round-14 best): 64x128 tile, BK=32, 4 waves, wave-tile 32x64, swizzled
// DMA slices (conflict-free), global_load_lds double-buffer, one barrier/iter,
// hw-transcendental epilogue, Q/K direct split-bf16 + in-kernel GT transpose.
// Round-15 lesson: phase-staggered K-loops REGRESSED (L2 locality loss,
// FETCH 69->114 MB) -> sequential K order restored.
__global__ __launch_bounds__(256, 3) void gemm_mfma_kernel(
    const unsigned short* __restrict__ Xhi, const unsigned short* __restrict__ Xlo,
    const unsigned short* __restrict__ ZThi, const unsigned short* __restrict__ ZTlo,
    const float* __restrict__ acol, const float* __restrict__ bcol, const float* __restrict__ scol,
    const float* __restrict__ cx2,
    unsigned short* __restrict__ Qhi, unsigned short* __restrict__ Qlo,
    unsigned short* __restrict__ Khi, unsigned short* __restrict__ Klo,
    unsigned short* __restrict__ GThi, unsigned short* __restrict__ GTlo,
    float* __restrict__ q2, float* __restrict__ k2, float* __restrict__ gm1)
{
  // per buffer (halfwords): Xh [0,2048) Xl [2048,4096) Zh [4096,8192) Zl [8192,12288)
  __shared__ unsigned short S[2][12288];     // 48 KB -> 3 blocks/CU

  const int mat = blockIdx.z;
  float* Stat = (mat == 0) ? q2 : ((mat == 1) ? k2 : gm1);
  unsigned short* Bh = (mat == 0) ? Qhi : Khi;
  unsigned short* Bl = (mat == 0) ? Qlo : Klo;

  const int n0 = blockIdx.x * 128;
  const int m0 = blockIdx.y * 64;
  const int tid = threadIdx.x;
  const int wave = tid >> 6, lane = tid & 63;
  const int tx = lane & 15, quad = lane >> 4;
  const int wrow = wave & 1;                 // rows [32*wrow, +32)
  const int wcol = wave >> 1;                // cols [64*wcol, +64) = head wcol

  // DMA slice mapping with chunk swizzle: row r = lane>>2, global chunk
  // c = ((lane&3) - (r>>1)) & 3  (stored at physical chunk lane&3).
  const int l4r = lane >> 2;
  const int l4c = 8 * (((lane & 3) - (l4r >> 1)) & 3);
  auto slice_ptr = [&](int si) -> const unsigned short* {
    if (si < 8) {
      const unsigned short* base = (si < 4) ? Xhi : Xlo;
      const int r16 = (si & 3) * 16;
      return base + (size_t)(m0 + r16 + l4r) * DD + l4c;
    } else {
      const unsigned short* base = (si < 16) ? ZThi : ZTlo;
      const int r16 = ((si - 8) & 7) * 16;
      return base + ((size_t)mat * DD + n0 + r16 + l4r) * DD + l4c;
    }
  };
  const int s0 = 6 * wave;
  const unsigned short* p0 = slice_ptr(s0 + 0);
  const unsigned short* p1 = slice_ptr(s0 + 1);
  const unsigned short* p2 = slice_ptr(s0 + 2);
  const unsigned short* p3 = slice_ptr(s0 + 3);
  const unsigned short* p4 = slice_ptr(s0 + 4);
  const unsigned short* p5 = slice_ptr(s0 + 5);
  const int o0 = 512 * (s0 + 0), o1 = 512 * (s0 + 1), o2 = 512 * (s0 + 2);
  const int o3 = 512 * (s0 + 3), o4 = 512 * (s0 + 4), o5 = 512 * (s0 + 5);

  // frag-read chunk offset: physical chunk of global chunk `quad` for row tx
  const int koff = 8 * ((quad + (tx >> 1)) & 3);

  const f32x4 z4 = {0.f, 0.f, 0.f, 0.f};
  f32x4 d00 = z4, d01 = z4, d02 = z4, d03 = z4;   // mb=0
  f32x4 d10 = z4, d11 = z4, d12 = z4, d13 = z4;   // mb=1

  async_copy16(p0, &S[0][o0]); async_copy16(p1, &S[0][o1]); async_copy16(p2, &S[0][o2]);
  async_copy16(p3, &S[0][o3]); async_copy16(p4, &S[0][o4]); async_copy16(p5, &S[0][o5]);
  p0 += 32; p1 += 32; p2 += 32; p3 += 32; p4 += 32; p5 += 32;

  for (int kt = 0; kt < 32; ++kt) {
    __syncthreads();
    if (kt < 31) {
      unsigned short* Bn = S[(kt + 1) & 1];
      async_copy16(p0, Bn + o0); async_copy16(p1, Bn + o1); async_copy16(p2, Bn + o2);
      async_copy16(p3, Bn + o3); async_copy16(p4, Bn + o4); async_copy16(p5, Bn + o5);
      p0 += 32; p1 += 32; p2 += 32; p3 += 32; p4 += 32; p5 += 32;
    }
    const unsigned short* Bc = S[kt & 1];
    const int ar = 32 * wrow + tx;
    bf16x8 a_h0 = *(const bf16x8*)&Bc[ar * 32 + koff];
    bf16x8 a_l0 = *(const bf16x8*)&Bc[2048 + ar * 32 + koff];
    bf16x8 a_h1 = *(const bf16x8*)&Bc[(ar + 16) * 32 + koff];
    bf16x8 a_l1 = *(const bf16x8*)&Bc[2048 + (ar + 16) * 32 + koff];

#define DO_NB(NB, C0, C1) { \
      const int brow = 16 * (4 * wcol + NB) + tx; \
      bf16x8 b_h = *(const bf16x8*)&Bc[4096 + brow * 32 + koff]; \
      bf16x8 b_l = *(const bf16x8*)&Bc[8192 + brow * 32 + koff]; \
      C0 = __builtin_amdgcn_mfma_f32_16x16x32_bf16(a_h0, b_h, C0, 0, 0, 0); \
      C0 = __builtin_amdgcn_mfma_f32_16x16x32_bf16(a_h0, b_l, C0, 0, 0, 0); \
      C0 = __builtin_amdgcn_mfma_f32_16x16x32_bf16(a_l0, b_h, C0, 0, 0, 0); \
      C1 = __builtin_amdgcn_mfma_f32_16x16x32_bf16(a_h1, b_h, C1, 0, 0, 0); \
      C1 = __builtin_amdgcn_mfma_f32_16x16x32_bf16(a_h1, b_l, C1, 0, 0, 0); \
      C1 = __builtin_amdgcn_mfma_f32_16x16x32_bf16(a_l1, b_h, C1, 0, 0, 0); }
    DO_NB(0, d00, d10)
    DO_NB(1, d01, d11)
    DO_NB(2, d02, d12)
    DO_NB(3, d03, d13)
#undef DO_NB
  }

  const int head = blockIdx.x * 2 + wcol;
  unsigned* Tr = (unsigned*)&S[0][0];        // reuse staging LDS (mat==2 only)
  if (mat == 2) __syncthreads();             // all waves done with S before reuse

  #pragma unroll
  for (int mb = 0; mb < 2; ++mb) {
    const f32x4 e0 = mb ? d10 : d00;
    const f32x4 e1 = mb ? d11 : d01;
    const f32x4 e2 = mb ? d12 : d02;
    const f32x4 e3 = mb ? d13 : d03;
    #pragma unroll
    for (int r = 0; r < 4; ++r) {
      const int sl = 32 * wrow + 16 * mb + 4 * quad + r;
      const int row = m0 + sl;
      const float c2 = cx2[row];
      const float inv = 1.0f / fmaxf(1.0f - c2, 1e-15f);
      const float onec = 1.0f + c2;
      float yv[4];
      #pragma unroll
      for (int nb = 0; nb < 4; ++nb) {
        const float accv = (nb == 0) ? e0[r] : (nb == 1) ? e1[r] : (nb == 2) ? e2[r] : e3[r];
        const int col = mat * DD + n0 + 64 * wcol + 16 * nb + tx;
        const float u = fmaf(accv, acol[col], -(onec * bcol[col])) * inv;
        const float a = fabsf(u);
        const float t = a + sqrtf(fmaf(a, a, 1.0f));
        const float p = __builtin_amdgcn_exp2f(scol[col] * __builtin_amdgcn_logf(t));
        float y = 0.5f * (p - __builtin_amdgcn_rcpf(p));
        yv[nb] = copysignf(y, u);
      }
      const int b = row >> 10, s = row & 1023;
      float n2 = 0.f;
      #pragma unroll
      for (int j = 0; j < 4; ++j) n2 = fmaf(yv[j], yv[j], n2);
      n2 = xor_sum16(n2);
      float n = fmaxf(sqrtf(n2), 1e-15f);
      float s1 = (n > MAXN) ? (MAXN / n) : 1.0f;      // project #1
      n2 = n2 * s1 * s1;
      float f = 1.0f / (1.0f + sqrtf(1.0f + n2));     // exp-map scaling
      float fs = s1 * f;
      n2 = n2 * f * f;
      float nb2 = fmaxf(sqrtf(n2), 1e-15f);
      float s2f = (nb2 > MAXN) ? (MAXN / nb2) : 1.0f; // project #2
      fs *= s2f;
      n2 = n2 * s2f * s2f;

      const size_t bh = (size_t)(b * NH + head);
      const size_t outbase = (bh * SS + s) * DH;
      if (mat == 2) {
        const float gamma = 2.0f / fmaxf(1.0f - n2, 1e-15f);
        #pragma unroll
        for (int j = 0; j < 4; ++j) {
          const float v = yv[j] * fs * gamma;
          const unsigned short hi = f2bf(v);
          const unsigned short lo = f2bf(v - bf2f(hi));
          Tr[(wcol * 64 + sl) * 65 + 16 * j + tx] = ((unsigned)lo << 16) | (unsigned)hi;
        }
        if (tx == 0) Stat[bh * SS + s] = gamma - 1.0f;
      } else {
        #pragma unroll
        for (int j = 0; j < 4; ++j) {
          const float v = yv[j] * fs;
          const unsigned short hi = f2bf(v);
          const unsigned short lo = f2bf(v - bf2f(hi));
          Bh[outbase + 16 * j + tx] = hi;
          Bl[outbase + 16 * j + tx] = lo;
        }
        if (tx == 0) Stat[bh * SS + s] = n2;
      }
    }
  }

  if (mat == 2) {                            // cooperative transposed writeout
    __syncthreads();
    const int bb = m0 >> 10, sbase = m0 & 1023;
    #pragma unroll
    for (int i = 0; i < 2; ++i) {
      const int task = tid + 256 * i;        // 512 tasks: 128 (h,dh) rows x 4 s-chunks
      const int rowid = task >> 2;
      const int hh = rowid >> 6, dh = rowid & 63;
      const int sc = (task & 3) * 16;
      unsigned short hbuf[16] __attribute__((aligned(16)));
      unsigned short lbuf[16] __attribute__((aligned(16)));
      #pragma unroll
      for (int s = 0; s < 16; ++s) {
        unsigned u = Tr[(hh * 64 + sc + s) * 65 + dh];
        hbuf[s] = (unsigned short)(u & 0xFFFFu);
        lbuf[s] = (unsigned short)(u >> 16);
      }
      const int hg = blockIdx.x * 2 + hh;
      const size_t ob = (((size_t)(bb * NH + hg)) * DH + dh) * SS + sbase + sc;
      *(uint4*)(GThi + ob)     = *(uint4*)&hbuf[0];
      *(uint4*)(GThi + ob + 8) = *(uint4*)&hbuf[8];
      *(uint4*)(GTlo + ob)     = *(uint4*)&lbuf[0];
      *(uint4*)(GTlo + ob + 8) = *(uint4*)&lbuf[8];
    }
  }
}

// ---------------- K3: MFMA flash-style hyperbolic attention (round-14 best) ----------
// LDK=88 bank spread; register prefetch of next K/G tile; Ps own region;
// 2 barriers/iter; sequential key order (round-15 stagger reverted).
__global__ __launch_bounds__(256) void flash_attn_kernel(
    const unsigned short* __restrict__ Qhi, const unsigned short* __restrict__ Qlo,
    const unsigned short* __restrict__ Khi, const unsigned short* __restrict__ Klo,
    const unsigned short* __restrict__ GThi, const unsigned short* __restrict__ GTlo,
    const float* __restrict__ q2a, const float* __restrict__ k2a, const float* __restrict__ gm1a,
    const float* __restrict__ mask, float* __restrict__ out)
{
  constexpr int LDK = 88;
  __shared__ unsigned short Ks_hi[64 * LDK];
  __shared__ unsigned short Ks_lo[64 * LDK];
  __shared__ unsigned short Gs_hi[64 * LDK];
  __shared__ unsigned short Gs_lo[64 * LDK];
  __shared__ unsigned short Ps_hi[64 * LDK];
  __shared__ unsigned short Ps_lo[64 * LDK];
  __shared__ float k2s[64], ik2s[64], gm1s[64], ems[64];

  const int qt = blockIdx.x, h = blockIdx.y, b = blockIdx.z;
  const int bh = b * NH + h;
  const int tid = threadIdx.x;
  const int wave = tid >> 6, lane = tid & 63;
  const int tx = lane & 15, quad = lane >> 4;
  const int r0 = qt * 64;

  bf16x8 qa_h[2], qa_l[2];
  {
    const size_t qoff = ((size_t)bh * SS + r0 + 16 * wave + tx) * DH;
    #pragma unroll
    for (int kc = 0; kc < 2; ++kc) {
      qa_h[kc] = *(const bf16x8*)(Qhi + qoff + 32 * kc + 8 * quad);
      qa_l[kc] = *(const bf16x8*)(Qlo + qoff + 32 * kc + 8 * quad);
    }
  }
  float q2r[4], iq2[4];
  #pragma unroll
  for (int r = 0; r < 4; ++r) {
    q2r[r] = q2a[(size_t)bh * SS + r0 + 16 * wave + 4 * quad + r];
    iq2[r] = 2.0f / fmaxf(1.0f - q2r[r], 1e-15f);
  }

  const f32x4 zero4 = {0.f, 0.f, 0.f, 0.f};
  f32x4 oacc[4] = {zero4, zero4, zero4, zero4};
  float dden[4] = {0.f, 0.f, 0.f, 0.f};

  const int c0 = tid, c1 = tid + 256;
  const int sr0 = c0 >> 3, sc0 = (c0 & 7) * 8;
  const int sr1 = c1 >> 3, sc1 = (c1 & 7) * 8;

  const size_t kbase = (size_t)bh * SS * DH;
  const size_t gbase = (size_t)bh * DH * SS;

  // prologue prefetch (tile 0)
  uint4 pk_h0 = *(const uint4*)(Khi + kbase + (size_t)sr0 * DH + sc0);
  uint4 pk_h1 = *(const uint4*)(Khi + kbase + (size_t)sr1 * DH + sc1);
  uint4 pk_l0 = *(const uint4*)(Klo + kbase + (size_t)sr0 * DH + sc0);
  uint4 pk_l1 = *(const uint4*)(Klo + kbase + (size_t)sr1 * DH + sc1);
  uint4 pg_h0 = *(const uint4*)(GThi + gbase + (size_t)sr0 * SS + sc0);
  uint4 pg_h1 = *(const uint4*)(GThi + gbase + (size_t)sr1 * SS + sc1);
  uint4 pg_l0 = *(const uint4*)(GTlo + gbase + (size_t)sr0 * SS + sc0);
  uint4 pg_l1 = *(const uint4*)(GTlo + gbase + (size_t)sr1 * SS + sc1);
  float p_k2 = 0.f, p_gm1 = 0.f, p_ms = 0.f;
  if (tid < 64) {
    p_k2  = k2a[(size_t)bh * SS + tid];
    p_gm1 = gm1a[(size_t)bh * SS + tid];
    p_ms  = mask[(size_t)b * SS + tid];
  }

  for (int kt = 0; kt < 16; ++kt) {
    __syncthreads();                         // prev tile fully consumed
    *(uint4*)&Ks_hi[sr0 * LDK + sc0] = pk_h0;
    *(uint4*)&Ks_hi[sr1 * LDK + sc1] = pk_h1;
    *(uint4*)&Ks_lo[sr0 * LDK + sc0] = pk_l0;
    *(uint4*)&Ks_lo[sr1 * LDK + sc1] = pk_l1;
    *(uint4*)&Gs_hi[sr0 * LDK + sc0] = pg_h0;
    *(uint4*)&Gs_hi[sr1 * LDK + sc1] = pg_h1;
    *(uint4*)&Gs_lo[sr0 * LDK + sc0] = pg_l0;
    *(uint4*)&Gs_lo[sr1 * LDK + sc1] = pg_l1;
    if (tid < 64) {
      k2s[tid]  = p_k2;
      ik2s[tid] = 1.0f / fmaxf(1.0f - p_k2, 1e-15f);
      gm1s[tid] = p_gm1;
      ems[tid]  = __expf(p_ms);
    }
    __syncthreads();                         // tile ready
    if (kt < 15) {                           // prefetch kt+1 before the compute phase
      const int t1 = (kt + 1) * 64;
      const size_t kb_ = kbase + (size_t)t1 * DH;
      const size_t gb_ = gbase + t1;
      pk_h0 = *(const uint4*)(Khi + kb_ + (size_t)sr0 * DH + sc0);
      pk_h1 = *(const uint4*)(Khi + kb_ + (size_t)sr1 * DH + sc1);
      pk_l0 = *(const uint4*)(Klo + kb_ + (size_t)sr0 * DH + sc0);
      pk_l1 = *(const uint4*)(Klo + kb_ + (size_t)sr1 * DH + sc1);
      pg_h0 = *(const uint4*)(GThi + gb_ + (size_t)sr0 * SS + sc0);
      pg_h1 = *(const uint4*)(GThi + gb_ + (size_t)sr1 * SS + sc1);
      pg_l0 = *(const uint4*)(GTlo + gb_ + (size_t)sr0 * SS + sc0);
      pg_l1 = *(const uint4*)(GTlo + gb_ + (size_t)sr1 * SS + sc1);
      if (tid < 64) {
        p_k2  = k2a[(size_t)bh * SS + t1 + tid];
        p_gm1 = gm1a[(size_t)bh * SS + t1 + tid];
        p_ms  = mask[(size_t)b * SS + t1 + tid];
      }
    }

    f32x4 sacc[4] = {zero4, zero4, zero4, zero4};
    #pragma unroll
    for (int kc = 0; kc < 2; ++kc) {
      const int ko = 32 * kc + 8 * quad;
      #pragma unroll
      for (int nb = 0; nb < 4; ++nb) {
        bf16x8 kh = *(const bf16x8*)&Ks_hi[(16 * nb + tx) * LDK + ko];
        bf16x8 kl = *(const bf16x8*)&Ks_lo[(16 * nb + tx) * LDK + ko];
        sacc[nb] = __builtin_amdgcn_mfma_f32_16x16x32_bf16(qa_h[kc], kh, sacc[nb], 0, 0, 0);
        sacc[nb] = __builtin_amdgcn_mfma_f32_16x16x32_bf16(qa_h[kc], kl, sacc[nb], 0, 0, 0);
        sacc[nb] = __builtin_amdgcn_mfma_f32_16x16x32_bf16(qa_l[kc], kh, sacc[nb], 0, 0, 0);
      }
    }

    float pb[4][4];
    #pragma unroll
    for (int nb = 0; nb < 4; ++nb) {
      const int key = 16 * nb + tx;
      const float k2v = k2s[key], ikv = ik2s[key], emv = ems[key], gmv = gm1s[key];
      #pragma unroll
      for (int r = 0; r < 4; ++r) {
        float sv = sacc[nb][r];
        float num = fmaxf(fmaf(-2.0f, sv, q2r[r] + k2v), 1e-15f);
        float e = num * iq2[r] * ikv;
        float g = fmaf(e, e, e + e);
        float z = 1.0f + e + __builtin_amdgcn_sqrtf(g);
        float w = emv * __builtin_amdgcn_rcpf(z);
        pb[r][nb] = w;
        dden[r] = fmaf(w, gmv, dden[r]);
      }
    }

    // write P into its own region; wave w owns rows [16w,16w+16) exclusively
    #pragma unroll
    for (int r = 0; r < 4; ++r) {
      const int prow = 16 * wave + 4 * quad + r;
      #pragma unroll
      for (int nb = 0; nb < 4; ++nb) {
        float w = pb[r][nb];
        unsigned short hi = f2bf(w);
        unsigned short lo = f2bf(w - bf2f(hi));
        Ps_hi[prow * LDK + 16 * nb + tx] = hi;
        Ps_lo[prow * LDK + 16 * nb + tx] = lo;
      }
    }
    // PV: same-wave LDS RAW only -> no barrier needed
    #pragma unroll
    for (int kc = 0; kc < 2; ++kc) {
      const int ko = 32 * kc + 8 * quad;
      bf16x8 ph = *(const bf16x8*)&Ps_hi[(16 * wave + tx) * LDK + ko];
      bf16x8 pl = *(const bf16x8*)&Ps_lo[(16 * wave + tx) * LDK + ko];
      #pragma unroll
      for (int nb = 0; nb < 4; ++nb) {
        bf16x8 gh = *(const bf16x8*)&Gs_hi[(16 * nb + tx) * LDK + ko];
        bf16x8 gl = *(const bf16x8*)&Gs_lo[(16 * nb + tx) * LDK + ko];
        oacc[nb] = __builtin_amdgcn_mfma_f32_16x16x32_bf16(ph, gh, oacc[nb], 0, 0, 0);
        oacc[nb] = __builtin_amdgcn_mfma_f32_16x16x32_bf16(ph, gl, oacc[nb], 0, 0, 0);
        oacc[nb] = __builtin_amdgcn_mfma_f32_16x16x32_bf16(pl, gh, oacc[nb], 0, 0, 0);
      }
    }
  }

  #pragma unroll
  for (int r = 0; r < 4; ++r) {
    float d = fmaxf(xor_sum16(dden[r]), 1e-10f);
    float invd = 1.0f / d;
    float tm[4]; float sq = 0.f;
    #pragma unroll
    for (int nb = 0; nb < 4; ++nb) { tm[nb] = oacc[nb][r] * invd; sq = fmaf(tm[nb], tm[nb], sq); }
    sq = xor_sum16(sq);
    const float f = 1.0f / (1.0f + sqrtf(fmaxf(1.0f - sq, 1e-15f)));
    const float n2 = sq * f * f;
    const float n = fmaxf(sqrtf(n2), 1e-15f);
    const float s2 = (n > MAXN) ? (MAXN / n) : 1.0f;
    const float fs = f * s2;
    const int qrow = r0 + 16 * wave + 4 * quad + r;
    #pragma unroll
    for (int nb = 0; nb < 4; ++nb)
      out[((size_t)(b * SS + qrow)) * DD + h * DH + 16 * nb + tx] = tm[nb] * fs;
  }
}

// ---------------- host ----------------
extern "C" void kernel_launch(void* const* d_in, const int* in_sizes, int n_in,
                              void* d_out, int out_size, void* d_ws, size_t ws_size,
                              hipStream_t stream) {
  const float* hs   = (const float*)d_in[0];
  const float* mask = (const float*)d_in[1];
  const float* qz   = (const float*)d_in[2];
  const float* qr   = (const float*)d_in[3];
  const float* kz   = (const float*)d_in[4];
  const float* kr   = (const float*)d_in[5];
  const float* vz   = (const float*)d_in[6];
  const float* vr   = (const float*)d_in[7];
  float* out = (float*)d_out;

  float* ws = (float*)d_ws;
  const size_t nQKV = (size_t)BB * NH * SS * DH;   // 2,097,152
  const size_t nStat = (size_t)BB * NH * SS;       // 32,768

  // fp32 region
  float* q2  = ws;
  float* k2  = q2 + nStat;
  float* gm1 = k2 + nStat;
  float* acol = gm1 + nStat;         // 3*1024 each
  float* bcol = acol + 3 * DD;
  float* scol = bcol + 3 * DD;
  float* cx2 = scol + 3 * DD;        // 2048

  // bf16 region (halfwords). gemm reads X/ZT while writing Q/K/GT -> all distinct.
  unsigned short* sb   = (unsigned short*)(cx2 + 2048);   // 16B-aligned
  unsigned short* Qhi  = sb;                  // 2M each
  unsigned short* Qlo  = Qhi + nQKV;
  unsigned short* Khi  = Qlo + nQKV;
  unsigned short* Klo  = Khi + nQKV;
  unsigned short* GThi = Klo + nQKV;
  unsigned short* GTlo = GThi + nQKV;
  unsigned short* Xhi  = GTlo + nQKV;
  unsigned short* Xlo  = Xhi + nQKV;
  unsigned short* ZThi = Xlo + nQKV;          // 3M each
  unsigned short* ZTlo = ZThi + 3 * (size_t)DD * DD;  // total 22M shorts = 44 MB

  prep_kernel<<<dim3(1840), 256, 0, stream>>>(
      hs, qz, kz, vz, qr, kr, vr, acol, bcol, scol, cx2, Xhi, Xlo, ZThi, ZTlo);
  gemm_mfma_kernel<<<dim3(8, 32, 3), 256, 0, stream>>>(
      Xhi, Xlo, ZThi, ZTlo, acol, bcol, scol, cx2,
      Qhi, Qlo, Khi, Klo, GThi, GTlo, q2, k2, gm1);
  flash_attn_kernel<<<dim3(16, NH, BB), 256, 0, stream>>>(
      Qhi, Qlo, Khi, Klo, GThi, GTlo, q2, k2, gm1, mask, out);
}